// Round 7
// baseline (2295.718 us; speedup 1.0000x reference)
//
#include <hip/hip_runtime.h>
#include <hip/hip_bf16.h>
#include <math.h>

constexpr int NN = 100000;     // nodes
constexpr int NE = 3200000;    // edges
constexpr int HID = 256;
constexpr int NBLK = (NN + 255) / 256;   // 391

typedef __attribute__((ext_vector_type(8))) short short8;
typedef __attribute__((ext_vector_type(4))) float floatx4;
typedef __attribute__((ext_vector_type(8))) unsigned short ushort8v;

// ---- bf16 helpers (storage bf16, math fp32) -------------------------------
__device__ __forceinline__ float bf2f(unsigned short u) {
    unsigned int t = ((unsigned int)u) << 16;
    float f; __builtin_memcpy(&f, &t, 4); return f;
}
__device__ __forceinline__ unsigned short f2bf(float f) {
    unsigned int t; __builtin_memcpy(&t, &f, 4);
    unsigned int lsb = (t >> 16) & 1u;
    t += 0x7fffu + lsb;
    return (unsigned short)(t >> 16);
}

// async global->LDS, 16B per lane; lds base must be wave-uniform
__device__ __forceinline__ void llds16(const void* g, void* l) {
    __builtin_amdgcn_global_load_lds(
        (const __attribute__((address_space(1))) unsigned int*)g,
        (__attribute__((address_space(3))) unsigned int*)l, 16, 0, 0);
}

// ---------------------------------------------------------------------------
// Edge dtype detection (int64 vs int32 delivery)
// ---------------------------------------------------------------------------
__global__ void detect_i64(const int* __restrict__ ei, int* __restrict__ flag) {
    if (blockIdx.x == 0 && threadIdx.x == 0) {
        int z = 1;
        for (int i = 0; i < 64; ++i)
            if (ei[2 * i + 1] != 0) { z = 0; break; }
        *flag = z;
    }
}
__device__ __forceinline__ int load_edge(const int* ei, int is64, long long idx) {
    if (is64) return (int)(((const long long*)ei)[idx]);
    return ei[idx];
}

__global__ void zero_setup(int* __restrict__ cnt, int* __restrict__ cursor,
                           float* __restrict__ gsum) {
    int i = blockIdx.x * 256 + threadIdx.x;
    if (i < NN) { cnt[i] = 0; cursor[i] = 0; }
    if (i < HID) gsum[i] = 0.0f;
}

// ---------------------------------------------------------------------------
// Weight / input conversion to bf16
// ---------------------------------------------------------------------------
__global__ void conv_weights(const float* __restrict__ Wf, const float* __restrict__ Uf,
                             const float* __restrict__ Wh, const float* __restrict__ Uh,
                             const float* __restrict__ Win,
                             unsigned short* __restrict__ wcf,
                             unsigned short* __restrict__ wch,
                             unsigned short* __restrict__ wib) {
    int i = blockIdx.x * 256 + threadIdx.x;
    if (i < 256 * 512) {
        int n = i >> 9, k = i & 511;
        float vf = (k < 256) ? Wf[n * 256 + k] : Uf[n * 256 + k - 256];
        float vh = (k < 256) ? Wh[n * 256 + k] : Uh[n * 256 + k - 256];
        wcf[i] = f2bf(vf); wch[i] = f2bf(vh);
    }
    if (i < 128 * 128) wib[i] = f2bf(Win[i]);
}

__global__ void conv_x(const float* __restrict__ x, unsigned short* __restrict__ xb) {
    int i = blockIdx.x * 256 + threadIdx.x;
    if (i < NN * 128 / 4) {
        float4 v = ((const float4*)x)[i];
        ushort4 o;
        o.x = f2bf(v.x); o.y = f2bf(v.y); o.z = f2bf(v.z); o.w = f2bf(v.w);
        ((ushort4*)xb)[i] = o;
    }
}

// ---------------------------------------------------------------------------
// CSR construction (simple 100k-counter version; bucketed CSR was neutral)
// ---------------------------------------------------------------------------
__global__ void count_deg(const int* __restrict__ ei, const int* __restrict__ flag,
                          int* __restrict__ cnt) {
    int e = blockIdx.x * 256 + threadIdx.x;
    if (e >= NE) return;
    int is64 = *flag;
    int d = load_edge(ei, is64, (long long)NE + e);
    d = min(max(d, 0), NN - 1);
    atomicAdd(&cnt[d], 1);
}

__global__ void scan_k1(const int* __restrict__ cnt, int* __restrict__ loc,
                        int* __restrict__ bsum) {
    __shared__ int s[256];
    int b = blockIdx.x, t = threadIdx.x;
    int i = b * 256 + t;
    int v = (i < NN) ? cnt[i] : 0;
    s[t] = v;
    __syncthreads();
    for (int ofs = 1; ofs < 256; ofs <<= 1) {
        int tv = (t >= ofs) ? s[t - ofs] : 0;
        __syncthreads();
        s[t] += tv;
        __syncthreads();
    }
    if (i < NN) loc[i] = s[t] - v;
    if (t == 255) bsum[b] = s[255];
}
__global__ void scan_k2(const int* __restrict__ bsum, int* __restrict__ bpre) {
    __shared__ int s[512];
    int t = threadIdx.x;
    int v = (t < NBLK) ? bsum[t] : 0;
    s[t] = v;
    __syncthreads();
    for (int ofs = 1; ofs < 512; ofs <<= 1) {
        int tv = (t >= ofs) ? s[t - ofs] : 0;
        __syncthreads();
        s[t] += tv;
        __syncthreads();
    }
    if (t < NBLK) bpre[t] = s[t] - v;
    if (t == NBLK - 1) bpre[NBLK] = s[t];
}
__global__ void scan_k3(const int* __restrict__ loc, const int* __restrict__ bpre,
                        int* __restrict__ off) {
    int b = blockIdx.x, t = threadIdx.x;
    int i = b * 256 + t;
    if (i < NN) off[i] = loc[i] + bpre[b];
    if (b == 0 && t == 0) off[NN] = bpre[NBLK];
}

__global__ void fill_csr(const int* __restrict__ ei, const int* __restrict__ flag,
                         const int* __restrict__ off, int* __restrict__ cursor,
                         int* __restrict__ csr) {
    int e = blockIdx.x * 256 + threadIdx.x;
    if (e >= NE) return;
    int is64 = *flag;
    int s = load_edge(ei, is64, e);
    int d = load_edge(ei, is64, (long long)NE + e);
    s = min(max(s, 0), NN - 1);
    d = min(max(d, 0), NN - 1);
    int p = atomicAdd(&cursor[d], 1);
    csr[off[d] + p] = s;
}

// ---------------------------------------------------------------------------
// Aggregation: mean of h[src] rows per node. One wave per node; half-wave per
// edge row (ushort8/lane), 4 rows in flight.
// ---------------------------------------------------------------------------
__global__ __launch_bounds__(256)
void aggregate(const unsigned short* __restrict__ h, const int* __restrict__ off,
               const int* __restrict__ csr, unsigned short* __restrict__ m) {
    int node = blockIdx.x * 4 + (threadIdx.x >> 6);
    int lane = threadIdx.x & 63;
    int half = lane >> 5;
    int fl = lane & 31;
    int e0 = off[node], e1 = off[node + 1];
    float a0[8], a1[8];
#pragma unroll
    for (int k = 0; k < 8; ++k) { a0[k] = 0.f; a1[k] = 0.f; }
    int e = e0;
    for (; e + 8 <= e1; e += 8) {
        int s0 = csr[e + half];
        int s1 = csr[e + 2 + half];
        int s2 = csr[e + 4 + half];
        int s3 = csr[e + 6 + half];
        ushort8v v0 = *(const ushort8v*)(h + (size_t)s0 * HID + fl * 8);
        ushort8v v1 = *(const ushort8v*)(h + (size_t)s1 * HID + fl * 8);
        ushort8v v2 = *(const ushort8v*)(h + (size_t)s2 * HID + fl * 8);
        ushort8v v3 = *(const ushort8v*)(h + (size_t)s3 * HID + fl * 8);
#pragma unroll
        for (int k = 0; k < 8; ++k) {
            a0[k] += bf2f(v0[k]); a1[k] += bf2f(v1[k]);
            a0[k] += bf2f(v2[k]); a1[k] += bf2f(v3[k]);
        }
    }
    for (; e + 2 <= e1; e += 2) {
        int s0 = csr[e + half];
        ushort8v v0 = *(const ushort8v*)(h + (size_t)s0 * HID + fl * 8);
#pragma unroll
        for (int k = 0; k < 8; ++k) a0[k] += bf2f(v0[k]);
    }
    if (e < e1 && half == 0) {
        int s0 = csr[e];
        ushort8v v0 = *(const ushort8v*)(h + (size_t)s0 * HID + fl * 8);
#pragma unroll
        for (int k = 0; k < 8; ++k) a0[k] += bf2f(v0[k]);
    }
#pragma unroll
    for (int k = 0; k < 8; ++k) a0[k] += a1[k];
#pragma unroll
    for (int k = 0; k < 8; ++k) a0[k] += __shfl(a0[k], lane ^ 32, 64);
    float inv = 1.0f / (float)max(e1 - e0, 1);
    if (half == 0) {
        ushort8v o;
#pragma unroll
        for (int k = 0; k < 8; ++k) o[k] = f2bf(a0[k] * inv);
        *(ushort8v*)(m + (size_t)node * HID + fl * 8) = o;
    }
}

// ---------------------------------------------------------------------------
// Input-encode MFMA GEMM (K=128): h = relu(x @ W_in^T + b_in), pad to 256.
// 128x128 tile, r3/r6-proven.
// ---------------------------------------------------------------------------
__global__ __launch_bounds__(256)
void encode_mfma(const unsigned short* __restrict__ A0,
                 const unsigned short* __restrict__ Bw,
                 const float* __restrict__ bias,
                 unsigned short* __restrict__ Out) {
    __shared__ unsigned short As[128 * 32];
    __shared__ unsigned short Bs[128 * 32];
    const int tid = threadIdx.x;
    const int wave = tid >> 6, lane = tid & 63;
    const int wr = (wave >> 1) * 64, wc = (wave & 1) * 64;
    const int lq = lane >> 4, lm = lane & 15;
    const int rowBase = blockIdx.x * 128;

    floatx4 acc[4][4];
#pragma unroll
    for (int i = 0; i < 4; ++i)
#pragma unroll
        for (int j = 0; j < 4; ++j) {
            acc[i][j][0] = 0.f; acc[i][j][1] = 0.f;
            acc[i][j][2] = 0.f; acc[i][j][3] = 0.f;
        }

    for (int k0 = 0; k0 < 128; k0 += 32) {
#pragma unroll
        for (int q = 0; q < 2; ++q) {
            int id = wave * 128 + q * 64 + lane;
            int r = id >> 2, c = id & 3;
            int grow = rowBase + r;
            if (grow > NN - 1) grow = NN - 1;
            llds16(A0 + (size_t)grow * 128 + k0 + c * 8,
                   (char*)As + (size_t)(wave * 128 + q * 64) * 16);
            llds16(Bw + (size_t)r * 128 + k0 + c * 8,
                   (char*)Bs + (size_t)(wave * 128 + q * 64) * 16);
        }
        __syncthreads();
        short8 af[4], bfr[4];
#pragma unroll
        for (int i = 0; i < 4; ++i)
            af[i] = *(const short8*)&As[(wr + i * 16 + lm) * 32 + lq * 8];
#pragma unroll
        for (int j = 0; j < 4; ++j)
            bfr[j] = *(const short8*)&Bs[(wc + j * 16 + lm) * 32 + lq * 8];
#pragma unroll
        for (int i = 0; i < 4; ++i)
#pragma unroll
            for (int j = 0; j < 4; ++j)
                acc[i][j] = __builtin_amdgcn_mfma_f32_16x16x32_bf16(
                    af[i], bfr[j], acc[i][j], 0, 0, 0);
        __syncthreads();
    }
#pragma unroll
    for (int i = 0; i < 4; ++i)
#pragma unroll
        for (int r = 0; r < 4; ++r) {
            int row = rowBase + wr + i * 16 + lq * 4 + r;
            if (row >= NN) continue;
            size_t rb = (size_t)row * HID;
#pragma unroll
            for (int j = 0; j < 4; ++j) {
                int col = wc + j * 16 + lm;
                float v = acc[i][j][r] + bias[col];
                Out[rb + col] = f2bf(fmaxf(v, 0.f));
                Out[rb + col + 128] = 0;
            }
        }
}

// ---------------------------------------------------------------------------
// Single-phase MGU GEMMs, 64 rows x 256 cols per block (A read ONCE).
// Staging layout identical to r5's verified kernel; 4 waves, each 64 cols,
// 4x4 frags of 16x16x32 bf16 (64 acc regs only).
// ---------------------------------------------------------------------------
__global__ __launch_bounds__(256)
void gate64(const unsigned short* __restrict__ Mm,
            const unsigned short* __restrict__ H,
            const unsigned short* __restrict__ Wf,
            const float* __restrict__ bf_v,
            unsigned short* __restrict__ Ff,
            unsigned short* __restrict__ HF) {
    __shared__ unsigned short As[64 * 32];    // 4 KB
    __shared__ unsigned short Bs[256 * 32];   // 16 KB
    const int tid = threadIdx.x;
    const int wave = tid >> 6, lane = tid & 63;
    const int wcol = wave * 64;
    const int lq = lane >> 4, lm = lane & 15;
    const int rowBase = blockIdx.x * 64;
    const int srow = tid >> 2;
    const int skk = (tid & 3) * 8;
    int garow = rowBase + srow;
    if (garow > NN - 1) garow = NN - 1;

    floatx4 acc[4][4];
#pragma unroll
    for (int i = 0; i < 4; ++i)
#pragma unroll
        for (int j = 0; j < 4; ++j) {
            acc[i][j][0] = 0.f; acc[i][j][1] = 0.f;
            acc[i][j][2] = 0.f; acc[i][j][3] = 0.f;
        }

    for (int k0 = 0; k0 < 512; k0 += 32) {
        const unsigned short* Asrc = (k0 < 256) ? Mm : H;
        int kc = k0 & 255;
        llds16(Asrc + (size_t)garow * HID + kc + skk, (char*)As + wave * 1024);
#pragma unroll
        for (int q = 0; q < 4; ++q) {
            int id = wave * 256 + q * 64 + lane;   // 0..1023
            int n = id >> 2, bk = (id & 3) * 8;    // n: 0..255
            llds16(Wf + (size_t)n * 512 + k0 + bk,
                   (char*)Bs + (size_t)(wave * 256 + q * 64) * 16);
        }
        __syncthreads();
        short8 af[4], bfr[4];
#pragma unroll
        for (int i = 0; i < 4; ++i)
            af[i] = *(const short8*)&As[(i * 16 + lm) * 32 + lq * 8];
#pragma unroll
        for (int j = 0; j < 4; ++j)
            bfr[j] = *(const short8*)&Bs[(wcol + j * 16 + lm) * 32 + lq * 8];
#pragma unroll
        for (int i = 0; i < 4; ++i)
#pragma unroll
            for (int j = 0; j < 4; ++j)
                acc[i][j] = __builtin_amdgcn_mfma_f32_16x16x32_bf16(
                    af[i], bfr[j], acc[i][j], 0, 0, 0);
        __syncthreads();
    }

    // epilogue: f = sigmoid(S+b) -> Ff;  HF = f*h
#pragma unroll
    for (int j = 0; j < 4; ++j) {
        int col = wcol + j * 16 + lm;
        float bias = bf_v[col];
#pragma unroll
        for (int i = 0; i < 4; ++i)
#pragma unroll
            for (int r = 0; r < 4; ++r) {
                int row = rowBase + i * 16 + lq * 4 + r;
                if (row >= NN) continue;
                float v = acc[i][j][r] + bias;
                float f = 1.f / (1.f + __expf(-v));
                size_t a = (size_t)row * HID + col;
                float hv = bf2f(H[a]);
                Ff[a] = f2bf(f);
                HF[a] = f2bf(f * hv);
            }
    }
}

__global__ __launch_bounds__(256)
void cand64(const unsigned short* __restrict__ Mm,
            const unsigned short* __restrict__ HF,
            const unsigned short* __restrict__ Wh,
            const float* __restrict__ bh_v,
            const unsigned short* __restrict__ Ff,
            unsigned short* __restrict__ H) {
    __shared__ unsigned short As[64 * 32];
    __shared__ unsigned short Bs[256 * 32];
    const int tid = threadIdx.x;
    const int wave = tid >> 6, lane = tid & 63;
    const int wcol = wave * 64;
    const int lq = lane >> 4, lm = lane & 15;
    const int rowBase = blockIdx.x * 64;
    const int srow = tid >> 2;
    const int skk = (tid & 3) * 8;
    int garow = rowBase + srow;
    if (garow > NN - 1) garow = NN - 1;

    floatx4 acc[4][4];
#pragma unroll
    for (int i = 0; i < 4; ++i)
#pragma unroll
        for (int j = 0; j < 4; ++j) {
            acc[i][j][0] = 0.f; acc[i][j][1] = 0.f;
            acc[i][j][2] = 0.f; acc[i][j][3] = 0.f;
        }

    for (int k0 = 0; k0 < 512; k0 += 32) {
        const unsigned short* Asrc = (k0 < 256) ? Mm : HF;
        int kc = k0 & 255;
        llds16(Asrc + (size_t)garow * HID + kc + skk, (char*)As + wave * 1024);
#pragma unroll
        for (int q = 0; q < 4; ++q) {
            int id = wave * 256 + q * 64 + lane;
            int n = id >> 2, bk = (id & 3) * 8;
            llds16(Wh + (size_t)n * 512 + k0 + bk,
                   (char*)Bs + (size_t)(wave * 256 + q * 64) * 16);
        }
        __syncthreads();
        short8 af[4], bfr[4];
#pragma unroll
        for (int i = 0; i < 4; ++i)
            af[i] = *(const short8*)&As[(i * 16 + lm) * 32 + lq * 8];
#pragma unroll
        for (int j = 0; j < 4; ++j)
            bfr[j] = *(const short8*)&Bs[(wcol + j * 16 + lm) * 32 + lq * 8];
#pragma unroll
        for (int i = 0; i < 4; ++i)
#pragma unroll
            for (int j = 0; j < 4; ++j)
                acc[i][j] = __builtin_amdgcn_mfma_f32_16x16x32_bf16(
                    af[i], bfr[j], acc[i][j], 0, 0, 0);
        __syncthreads();
    }

    // epilogue: h = (1-f)*h + f*tanh(S+b)
#pragma unroll
    for (int j = 0; j < 4; ++j) {
        int col = wcol + j * 16 + lm;
        float bias = bh_v[col];
#pragma unroll
        for (int i = 0; i < 4; ++i)
#pragma unroll
            for (int r = 0; r < 4; ++r) {
                int row = rowBase + i * 16 + lq * 4 + r;
                if (row >= NN) continue;
                float v = acc[i][j][r] + bias;
                float xc = fminf(fmaxf(v, -12.f), 12.f);
                float e2 = __expf(2.f * xc);
                float t = (e2 - 1.f) / (e2 + 1.f);
                size_t a = (size_t)row * HID + col;
                float f = bf2f(Ff[a]);
                float hv = bf2f(H[a]);
                H[a] = f2bf((1.f - f) * hv + f * t);
            }
    }
}

// ---------------------------------------------------------------------------
// Readout
// ---------------------------------------------------------------------------
__global__ __launch_bounds__(256)
void colmean(const unsigned short* __restrict__ h, float* __restrict__ gsum) {
    int j = threadIdx.x;
    long long n0 = (long long)blockIdx.x * 256;
    float acc = 0.0f;
    for (int n = 0; n < 256; ++n) {
        long long node = n0 + n;
        if (node < NN) acc += bf2f(h[node * HID + j]);
    }
    atomicAdd(&gsum[j], acc);
}

__global__ __launch_bounds__(256)
void final_pred(const float* __restrict__ gsum, const float* __restrict__ Wp,
                const float* __restrict__ bp, float* __restrict__ out) {
    __shared__ float s[256];
    int j = threadIdx.x;
    s[j] = gsum[j] * (1.0f / (float)NN) * Wp[j];
    __syncthreads();
    for (int ofs = 128; ofs > 0; ofs >>= 1) {
        if (j < ofs) s[j] += s[j + ofs];
        __syncthreads();
    }
    if (j == 0) out[0] = s[0] + bp[0];
}

// ---------------------------------------------------------------------------
extern "C" void kernel_launch(void* const* d_in, const int* in_sizes, int n_in,
                              void* d_out, int out_size, void* d_ws, size_t ws_size,
                              hipStream_t stream) {
    const float* x      = (const float*)d_in[0];
    const int*   ei     = (const int*)d_in[1];
    const float* W_in   = (const float*)d_in[2];
    const float* b_in   = (const float*)d_in[3];
    const float* W_f    = (const float*)d_in[4];
    const float* U_f    = (const float*)d_in[5];
    const float* b_f    = (const float*)d_in[6];
    const float* W_h    = (const float*)d_in[7];
    const float* U_h    = (const float*)d_in[8];
    const float* b_h    = (const float*)d_in[9];
    const float* W_pred = (const float*)d_in[10];
    const float* b_pred = (const float*)d_in[11];
    float* out = (float*)d_out;

    char* p = (char*)d_ws;
    auto alloc = [&](size_t bytes) {
        char* r = p;
        p += (bytes + 511) & ~(size_t)511;
        return r;
    };
    int*            cnt    = (int*)alloc((size_t)NN * 4);
    int*            cursor = (int*)alloc((size_t)NN * 4);
    int*            off    = (int*)alloc((size_t)(NN + 1) * 4);
    int*            flag   = (int*)alloc(4);
    float*          gsum   = (float*)alloc(HID * 4);
    int*            loc    = (int*)alloc((size_t)NN * 4);
    int*            bsum   = (int*)alloc((size_t)NBLK * 4);
    int*            bpre   = (int*)alloc((size_t)(NBLK + 1) * 4);
    unsigned short* wcf    = (unsigned short*)alloc((size_t)256 * 512 * 2);
    unsigned short* wch    = (unsigned short*)alloc((size_t)256 * 512 * 2);
    unsigned short* wib    = (unsigned short*)alloc((size_t)128 * 128 * 2);
    int*            csr    = (int*)alloc((size_t)NE * 4);
    unsigned short* hbuf   = (unsigned short*)alloc((size_t)NN * HID * 2);
    unsigned short* mbuf   = (unsigned short*)alloc((size_t)NN * HID * 2);
    unsigned short* fbuf   = (unsigned short*)alloc((size_t)NN * HID * 2);
    unsigned short* hf     = (unsigned short*)alloc((size_t)NN * HID * 2);
    unsigned short* xb     = hf;   // x-bf16 (25.6MB) dead before hf first write

    detect_i64<<<1, 64, 0, stream>>>(ei, flag);
    zero_setup<<<NBLK, 256, 0, stream>>>(cnt, cursor, gsum);
    conv_weights<<<512, 256, 0, stream>>>(W_f, U_f, W_h, U_h, W_in, wcf, wch, wib);
    conv_x<<<(NN * 128 / 4 + 255) / 256, 256, 0, stream>>>(x, xb);

    count_deg<<<(NE + 255) / 256, 256, 0, stream>>>(ei, flag, cnt);
    scan_k1<<<NBLK, 256, 0, stream>>>(cnt, loc, bsum);
    scan_k2<<<1, 512, 0, stream>>>(bsum, bpre);
    scan_k3<<<NBLK, 256, 0, stream>>>(loc, bpre, off);
    fill_csr<<<(NE + 255) / 256, 256, 0, stream>>>(ei, flag, off, cursor, csr);

    encode_mfma<<<(NN + 127) / 128, 256, 0, stream>>>(xb, wib, b_in, hbuf);

    const int SBLK = (NN + 63) / 64;   // 1563
    for (int step = 0; step < 4; ++step) {
        aggregate<<<NN / 4, 256, 0, stream>>>(hbuf, off, csr, mbuf);
        gate64<<<SBLK, 256, 0, stream>>>(mbuf, hbuf, wcf, b_f, fbuf, hf);
        cand64<<<SBLK, 256, 0, stream>>>(mbuf, hf, wch, b_h, fbuf, hbuf);
    }

    colmean<<<NBLK, 256, 0, stream>>>(hbuf, gsum);
    final_pred<<<1, 256, 0, stream>>>(gsum, W_pred, b_pred, out);
}

// Round 8
// 2120.259 us; speedup vs baseline: 1.0828x; 1.0828x over previous
//
#include <hip/hip_runtime.h>
#include <hip/hip_bf16.h>
#include <math.h>

constexpr int NN = 100000;     // nodes
constexpr int NE = 3200000;    // edges
constexpr int HID = 256;
constexpr int NBLK = (NN + 255) / 256;   // 391

typedef __attribute__((ext_vector_type(8))) short short8;
typedef __attribute__((ext_vector_type(4))) float floatx4;
typedef __attribute__((ext_vector_type(8))) unsigned short ushort8v;

// ---- bf16 helpers (storage bf16, math fp32) -------------------------------
__device__ __forceinline__ float bf2f(unsigned short u) {
    unsigned int t = ((unsigned int)u) << 16;
    float f; __builtin_memcpy(&f, &t, 4); return f;
}
__device__ __forceinline__ unsigned short f2bf(float f) {
    unsigned int t; __builtin_memcpy(&t, &f, 4);
    unsigned int lsb = (t >> 16) & 1u;
    t += 0x7fffu + lsb;
    return (unsigned short)(t >> 16);
}

// async global->LDS, 16B per lane; lds base must be wave-uniform
__device__ __forceinline__ void llds16(const void* g, void* l) {
    __builtin_amdgcn_global_load_lds(
        (const __attribute__((address_space(1))) unsigned int*)g,
        (__attribute__((address_space(3))) unsigned int*)l, 16, 0, 0);
}

// ---------------------------------------------------------------------------
// Edge dtype detection (int64 vs int32 delivery)
// ---------------------------------------------------------------------------
__global__ void detect_i64(const int* __restrict__ ei, int* __restrict__ flag) {
    if (blockIdx.x == 0 && threadIdx.x == 0) {
        int z = 1;
        for (int i = 0; i < 64; ++i)
            if (ei[2 * i + 1] != 0) { z = 0; break; }
        *flag = z;
    }
}
__device__ __forceinline__ int load_edge(const int* ei, int is64, long long idx) {
    if (is64) return (int)(((const long long*)ei)[idx]);
    return ei[idx];
}

__global__ void zero_setup(int* __restrict__ cnt, int* __restrict__ cursor,
                           float* __restrict__ gsum) {
    int i = blockIdx.x * 256 + threadIdx.x;
    if (i < NN) { cnt[i] = 0; cursor[i] = 0; }
    if (i < HID) gsum[i] = 0.0f;
}

// ---------------------------------------------------------------------------
// Weight / input conversion to bf16
// ---------------------------------------------------------------------------
__global__ void conv_weights(const float* __restrict__ Wf, const float* __restrict__ Uf,
                             const float* __restrict__ Wh, const float* __restrict__ Uh,
                             const float* __restrict__ Win,
                             unsigned short* __restrict__ wcf,
                             unsigned short* __restrict__ wch,
                             unsigned short* __restrict__ wib) {
    int i = blockIdx.x * 256 + threadIdx.x;
    if (i < 256 * 512) {
        int n = i >> 9, k = i & 511;
        float vf = (k < 256) ? Wf[n * 256 + k] : Uf[n * 256 + k - 256];
        float vh = (k < 256) ? Wh[n * 256 + k] : Uh[n * 256 + k - 256];
        wcf[i] = f2bf(vf); wch[i] = f2bf(vh);
    }
    if (i < 128 * 128) wib[i] = f2bf(Win[i]);
}

__global__ void conv_x(const float* __restrict__ x, unsigned short* __restrict__ xb) {
    int i = blockIdx.x * 256 + threadIdx.x;
    if (i < NN * 128 / 4) {
        float4 v = ((const float4*)x)[i];
        ushort4 o;
        o.x = f2bf(v.x); o.y = f2bf(v.y); o.z = f2bf(v.z); o.w = f2bf(v.w);
        ((ushort4*)xb)[i] = o;
    }
}

// ---------------------------------------------------------------------------
// CSR construction
// ---------------------------------------------------------------------------
__global__ void count_deg(const int* __restrict__ ei, const int* __restrict__ flag,
                          int* __restrict__ cnt) {
    int e = blockIdx.x * 256 + threadIdx.x;
    if (e >= NE) return;
    int is64 = *flag;
    int d = load_edge(ei, is64, (long long)NE + e);
    d = min(max(d, 0), NN - 1);
    atomicAdd(&cnt[d], 1);
}

__global__ void scan_k1(const int* __restrict__ cnt, int* __restrict__ loc,
                        int* __restrict__ bsum) {
    __shared__ int s[256];
    int b = blockIdx.x, t = threadIdx.x;
    int i = b * 256 + t;
    int v = (i < NN) ? cnt[i] : 0;
    s[t] = v;
    __syncthreads();
    for (int ofs = 1; ofs < 256; ofs <<= 1) {
        int tv = (t >= ofs) ? s[t - ofs] : 0;
        __syncthreads();
        s[t] += tv;
        __syncthreads();
    }
    if (i < NN) loc[i] = s[t] - v;
    if (t == 255) bsum[b] = s[255];
}
__global__ void scan_k2(const int* __restrict__ bsum, int* __restrict__ bpre) {
    __shared__ int s[512];
    int t = threadIdx.x;
    int v = (t < NBLK) ? bsum[t] : 0;
    s[t] = v;
    __syncthreads();
    for (int ofs = 1; ofs < 512; ofs <<= 1) {
        int tv = (t >= ofs) ? s[t - ofs] : 0;
        __syncthreads();
        s[t] += tv;
        __syncthreads();
    }
    if (t < NBLK) bpre[t] = s[t] - v;
    if (t == NBLK - 1) bpre[NBLK] = s[t];
}
__global__ void scan_k3(const int* __restrict__ loc, const int* __restrict__ bpre,
                        int* __restrict__ off) {
    int b = blockIdx.x, t = threadIdx.x;
    int i = b * 256 + t;
    if (i < NN) off[i] = loc[i] + bpre[b];
    if (b == 0 && t == 0) off[NN] = bpre[NBLK];
}

__global__ void fill_csr(const int* __restrict__ ei, const int* __restrict__ flag,
                         const int* __restrict__ off, int* __restrict__ cursor,
                         int* __restrict__ csr) {
    int e = blockIdx.x * 256 + threadIdx.x;
    if (e >= NE) return;
    int is64 = *flag;
    int s = load_edge(ei, is64, e);
    int d = load_edge(ei, is64, (long long)NE + e);
    s = min(max(s, 0), NN - 1);
    d = min(max(d, 0), NN - 1);
    int p = atomicAdd(&cursor[d], 1);
    csr[off[d] + p] = s;
}

// ---------------------------------------------------------------------------
// Aggregation: mean of h[src] rows per node. One wave per node; half-wave per
// edge row (ushort8/lane), 8 rows in flight.
// ---------------------------------------------------------------------------
__global__ __launch_bounds__(256)
void aggregate(const unsigned short* __restrict__ h, const int* __restrict__ off,
               const int* __restrict__ csr, unsigned short* __restrict__ m) {
    int node = blockIdx.x * 4 + (threadIdx.x >> 6);
    int lane = threadIdx.x & 63;
    int half = lane >> 5;
    int fl = lane & 31;
    int e0 = off[node], e1 = off[node + 1];
    float a0[8], a1[8];
#pragma unroll
    for (int k = 0; k < 8; ++k) { a0[k] = 0.f; a1[k] = 0.f; }
    int e = e0;
    for (; e + 16 <= e1; e += 16) {
        int s0 = csr[e + half];
        int s1 = csr[e + 2 + half];
        int s2 = csr[e + 4 + half];
        int s3 = csr[e + 6 + half];
        int s4 = csr[e + 8 + half];
        int s5 = csr[e + 10 + half];
        int s6 = csr[e + 12 + half];
        int s7 = csr[e + 14 + half];
        ushort8v v0 = *(const ushort8v*)(h + (size_t)s0 * HID + fl * 8);
        ushort8v v1 = *(const ushort8v*)(h + (size_t)s1 * HID + fl * 8);
        ushort8v v2 = *(const ushort8v*)(h + (size_t)s2 * HID + fl * 8);
        ushort8v v3 = *(const ushort8v*)(h + (size_t)s3 * HID + fl * 8);
        ushort8v v4 = *(const ushort8v*)(h + (size_t)s4 * HID + fl * 8);
        ushort8v v5 = *(const ushort8v*)(h + (size_t)s5 * HID + fl * 8);
        ushort8v v6 = *(const ushort8v*)(h + (size_t)s6 * HID + fl * 8);
        ushort8v v7 = *(const ushort8v*)(h + (size_t)s7 * HID + fl * 8);
#pragma unroll
        for (int k = 0; k < 8; ++k) {
            a0[k] += bf2f(v0[k]); a1[k] += bf2f(v1[k]);
            a0[k] += bf2f(v2[k]); a1[k] += bf2f(v3[k]);
            a0[k] += bf2f(v4[k]); a1[k] += bf2f(v5[k]);
            a0[k] += bf2f(v6[k]); a1[k] += bf2f(v7[k]);
        }
    }
    for (; e + 2 <= e1; e += 2) {
        int s0 = csr[e + half];
        ushort8v v0 = *(const ushort8v*)(h + (size_t)s0 * HID + fl * 8);
#pragma unroll
        for (int k = 0; k < 8; ++k) a0[k] += bf2f(v0[k]);
    }
    if (e < e1 && half == 0) {
        int s0 = csr[e];
        ushort8v v0 = *(const ushort8v*)(h + (size_t)s0 * HID + fl * 8);
#pragma unroll
        for (int k = 0; k < 8; ++k) a0[k] += bf2f(v0[k]);
    }
#pragma unroll
    for (int k = 0; k < 8; ++k) a0[k] += a1[k];
#pragma unroll
    for (int k = 0; k < 8; ++k) a0[k] += __shfl(a0[k], lane ^ 32, 64);
    float inv = 1.0f / (float)max(e1 - e0, 1);
    if (half == 0) {
        ushort8v o;
#pragma unroll
        for (int k = 0; k < 8; ++k) o[k] = f2bf(a0[k] * inv);
        *(ushort8v*)(m + (size_t)node * HID + fl * 8) = o;
    }
}

// ---------------------------------------------------------------------------
// Input-encode MFMA GEMM (K=128): h = relu(x @ W_in^T + b_in), pad to 256.
// 128x128 tile, r3/r6-proven.
// ---------------------------------------------------------------------------
__global__ __launch_bounds__(256)
void encode_mfma(const unsigned short* __restrict__ A0,
                 const unsigned short* __restrict__ Bw,
                 const float* __restrict__ bias,
                 unsigned short* __restrict__ Out) {
    __shared__ unsigned short As[128 * 32];
    __shared__ unsigned short Bs[128 * 32];
    const int tid = threadIdx.x;
    const int wave = tid >> 6, lane = tid & 63;
    const int wr = (wave >> 1) * 64, wc = (wave & 1) * 64;
    const int lq = lane >> 4, lm = lane & 15;
    const int rowBase = blockIdx.x * 128;

    floatx4 acc[4][4];
#pragma unroll
    for (int i = 0; i < 4; ++i)
#pragma unroll
        for (int j = 0; j < 4; ++j) {
            acc[i][j][0] = 0.f; acc[i][j][1] = 0.f;
            acc[i][j][2] = 0.f; acc[i][j][3] = 0.f;
        }

    for (int k0 = 0; k0 < 128; k0 += 32) {
#pragma unroll
        for (int q = 0; q < 2; ++q) {
            int id = wave * 128 + q * 64 + lane;
            int r = id >> 2, c = id & 3;
            int grow = rowBase + r;
            if (grow > NN - 1) grow = NN - 1;
            llds16(A0 + (size_t)grow * 128 + k0 + c * 8,
                   (char*)As + (size_t)(wave * 128 + q * 64) * 16);
            llds16(Bw + (size_t)r * 128 + k0 + c * 8,
                   (char*)Bs + (size_t)(wave * 128 + q * 64) * 16);
        }
        __syncthreads();
        short8 af[4], bfr[4];
#pragma unroll
        for (int i = 0; i < 4; ++i)
            af[i] = *(const short8*)&As[(wr + i * 16 + lm) * 32 + lq * 8];
#pragma unroll
        for (int j = 0; j < 4; ++j)
            bfr[j] = *(const short8*)&Bs[(wc + j * 16 + lm) * 32 + lq * 8];
#pragma unroll
        for (int i = 0; i < 4; ++i)
#pragma unroll
            for (int j = 0; j < 4; ++j)
                acc[i][j] = __builtin_amdgcn_mfma_f32_16x16x32_bf16(
                    af[i], bfr[j], acc[i][j], 0, 0, 0);
        __syncthreads();
    }
#pragma unroll
    for (int i = 0; i < 4; ++i)
#pragma unroll
        for (int r = 0; r < 4; ++r) {
            int row = rowBase + wr + i * 16 + lq * 4 + r;
            if (row >= NN) continue;
            size_t rb = (size_t)row * HID;
#pragma unroll
            for (int j = 0; j < 4; ++j) {
                int col = wc + j * 16 + lm;
                float v = acc[i][j][r] + bias[col];
                Out[rb + col] = f2bf(fmaxf(v, 0.f));
                Out[rb + col + 128] = 0;
            }
        }
}

// ---------------------------------------------------------------------------
// MGU GEMMs: 128 rows x 256 cols per block, 512 threads (8 waves as 2x4 of
// 64x64 wave-tiles, 4x4 frags of 16x16x32, 64 acc VGPRs). A read ONCE per
// dispatch; B (0.25MB) L2-resident. LDS 24KB. __launch_bounds__(512,4) pins
// VGPR<=128 for 2 blocks/CU.
// MODE 0 (gate): f = sigmoid(S+b) -> Ff;  HF = f*Hh
// MODE 1 (cand): H = (1-f)*H + f*tanh(S+b)
// ---------------------------------------------------------------------------
template <int MODE>
__global__ __launch_bounds__(512, 4)
void mgu512(const unsigned short* __restrict__ Mm,
            const unsigned short* __restrict__ A1,   // gate: H ; cand: HF
            const unsigned short* __restrict__ Bw,
            const float* __restrict__ bias,
            unsigned short* __restrict__ Ff,         // gate: write ; cand: read
            unsigned short* __restrict__ HF,         // gate: write f*h
            unsigned short* __restrict__ H) {        // gate: read ; cand: r/w
    __shared__ unsigned short As[128 * 32];   // 8 KB  [row][k]
    __shared__ unsigned short Bs[256 * 32];   // 16 KB [col][k]
    const int tid = threadIdx.x;
    const int wave = tid >> 6, lane = tid & 63;
    const int wr = (wave >> 2) * 64;          // 2 row groups
    const int wc = (wave & 3) * 64;           // 4 col groups
    const int lq = lane >> 4, lm = lane & 15;
    const int rowBase = blockIdx.x * 128;

    // A staging map: 512 chunks (128 rows x 4 kchunks), 1 per thread
    const int sarow = tid >> 2;
    const int sakk = (tid & 3) * 8;
    int garow = rowBase + sarow;
    if (garow > NN - 1) garow = NN - 1;

    floatx4 acc[4][4];
#pragma unroll
    for (int i = 0; i < 4; ++i)
#pragma unroll
        for (int j = 0; j < 4; ++j) {
            acc[i][j][0] = 0.f; acc[i][j][1] = 0.f;
            acc[i][j][2] = 0.f; acc[i][j][3] = 0.f;
        }

    for (int k0 = 0; k0 < 512; k0 += 32) {
        const unsigned short* Asrc = (k0 < 256) ? Mm : A1;
        int kc = k0 & 255;
        // A: one 16B chunk per thread
        llds16(Asrc + (size_t)garow * HID + kc + sakk, (char*)As + wave * 1024);
        // B: two 16B chunks per thread (1024 chunks total)
#pragma unroll
        for (int q = 0; q < 2; ++q) {
            int cidx = q * 512 + wave * 64 + lane;   // 0..1023
            int n = cidx >> 2, bk = (cidx & 3) * 8;  // n: 0..255
            llds16(Bw + (size_t)n * 512 + k0 + bk,
                   (char*)Bs + (size_t)(q * 512 + wave * 64) * 16);
        }
        __syncthreads();
        short8 af[4];
#pragma unroll
        for (int i = 0; i < 4; ++i)
            af[i] = *(const short8*)&As[(wr + i * 16 + lm) * 32 + lq * 8];
#pragma unroll
        for (int j = 0; j < 4; ++j) {
            short8 bfr = *(const short8*)&Bs[(wc + j * 16 + lm) * 32 + lq * 8];
#pragma unroll
            for (int i = 0; i < 4; ++i)
                acc[i][j] = __builtin_amdgcn_mfma_f32_16x16x32_bf16(
                    af[i], bfr, acc[i][j], 0, 0, 0);
        }
        __syncthreads();
    }

    // epilogue
#pragma unroll
    for (int j = 0; j < 4; ++j) {
        int col = wc + j * 16 + lm;
        float b = bias[col];
#pragma unroll
        for (int i = 0; i < 4; ++i)
#pragma unroll
            for (int r = 0; r < 4; ++r) {
                int row = rowBase + wr + i * 16 + lq * 4 + r;
                if (row >= NN) continue;
                size_t a = (size_t)row * HID + col;
                float v = acc[i][j][r] + b;
                if (MODE == 0) {
                    float f = 1.f / (1.f + __expf(-v));
                    float hv = bf2f(H[a]);
                    Ff[a] = f2bf(f);
                    HF[a] = f2bf(f * hv);
                } else {
                    float xc = fminf(fmaxf(v, -12.f), 12.f);
                    float e2 = __expf(2.f * xc);
                    float t = (e2 - 1.f) / (e2 + 1.f);
                    float f = bf2f(Ff[a]);
                    float hv = bf2f(H[a]);
                    H[a] = f2bf((1.f - f) * hv + f * t);
                }
            }
    }
}

// ---------------------------------------------------------------------------
// Readout
// ---------------------------------------------------------------------------
__global__ __launch_bounds__(256)
void colmean(const unsigned short* __restrict__ h, float* __restrict__ gsum) {
    int j = threadIdx.x;
    long long n0 = (long long)blockIdx.x * 256;
    float acc = 0.0f;
    for (int n = 0; n < 256; ++n) {
        long long node = n0 + n;
        if (node < NN) acc += bf2f(h[node * HID + j]);
    }
    atomicAdd(&gsum[j], acc);
}

__global__ __launch_bounds__(256)
void final_pred(const float* __restrict__ gsum, const float* __restrict__ Wp,
                const float* __restrict__ bp, float* __restrict__ out) {
    __shared__ float s[256];
    int j = threadIdx.x;
    s[j] = gsum[j] * (1.0f / (float)NN) * Wp[j];
    __syncthreads();
    for (int ofs = 128; ofs > 0; ofs >>= 1) {
        if (j < ofs) s[j] += s[j + ofs];
        __syncthreads();
    }
    if (j == 0) out[0] = s[0] + bp[0];
}

// ---------------------------------------------------------------------------
extern "C" void kernel_launch(void* const* d_in, const int* in_sizes, int n_in,
                              void* d_out, int out_size, void* d_ws, size_t ws_size,
                              hipStream_t stream) {
    const float* x      = (const float*)d_in[0];
    const int*   ei     = (const int*)d_in[1];
    const float* W_in   = (const float*)d_in[2];
    const float* b_in   = (const float*)d_in[3];
    const float* W_f    = (const float*)d_in[4];
    const float* U_f    = (const float*)d_in[5];
    const float* b_f    = (const float*)d_in[6];
    const float* W_h    = (const float*)d_in[7];
    const float* U_h    = (const float*)d_in[8];
    const float* b_h    = (const float*)d_in[9];
    const float* W_pred = (const float*)d_in[10];
    const float* b_pred = (const float*)d_in[11];
    float* out = (float*)d_out;

    char* p = (char*)d_ws;
    auto alloc = [&](size_t bytes) {
        char* r = p;
        p += (bytes + 511) & ~(size_t)511;
        return r;
    };
    int*            cnt    = (int*)alloc((size_t)NN * 4);
    int*            cursor = (int*)alloc((size_t)NN * 4);
    int*            off    = (int*)alloc((size_t)(NN + 1) * 4);
    int*            flag   = (int*)alloc(4);
    float*          gsum   = (float*)alloc(HID * 4);
    int*            loc    = (int*)alloc((size_t)NN * 4);
    int*            bsum   = (int*)alloc((size_t)NBLK * 4);
    int*            bpre   = (int*)alloc((size_t)(NBLK + 1) * 4);
    unsigned short* wcf    = (unsigned short*)alloc((size_t)256 * 512 * 2);
    unsigned short* wch    = (unsigned short*)alloc((size_t)256 * 512 * 2);
    unsigned short* wib    = (unsigned short*)alloc((size_t)128 * 128 * 2);
    int*            csr    = (int*)alloc((size_t)NE * 4);
    unsigned short* hbuf   = (unsigned short*)alloc((size_t)NN * HID * 2);
    unsigned short* mbuf   = (unsigned short*)alloc((size_t)NN * HID * 2);
    unsigned short* fbuf   = (unsigned short*)alloc((size_t)NN * HID * 2);
    unsigned short* hf     = (unsigned short*)alloc((size_t)NN * HID * 2);
    unsigned short* xb     = hf;   // x-bf16 (25.6MB) dead before hf first write

    detect_i64<<<1, 64, 0, stream>>>(ei, flag);
    zero_setup<<<NBLK, 256, 0, stream>>>(cnt, cursor, gsum);
    conv_weights<<<512, 256, 0, stream>>>(W_f, U_f, W_h, U_h, W_in, wcf, wch, wib);
    conv_x<<<(NN * 128 / 4 + 255) / 256, 256, 0, stream>>>(x, xb);

    count_deg<<<(NE + 255) / 256, 256, 0, stream>>>(ei, flag, cnt);
    scan_k1<<<NBLK, 256, 0, stream>>>(cnt, loc, bsum);
    scan_k2<<<1, 512, 0, stream>>>(bsum, bpre);
    scan_k3<<<NBLK, 256, 0, stream>>>(loc, bpre, off);
    fill_csr<<<(NE + 255) / 256, 256, 0, stream>>>(ei, flag, off, cursor, csr);

    encode_mfma<<<(NN + 127) / 128, 256, 0, stream>>>(xb, wib, b_in, hbuf);

    const int GBLK = (NN + 127) / 128;   // 782
    for (int step = 0; step < 4; ++step) {
        aggregate<<<NN / 4, 256, 0, stream>>>(hbuf, off, csr, mbuf);
        mgu512<0><<<GBLK, 512, 0, stream>>>(mbuf, hbuf, wcf, b_f, fbuf, hf, hbuf);
        mgu512<1><<<GBLK, 512, 0, stream>>>(mbuf, hf, wch, b_h, fbuf, nullptr, hbuf);
    }

    colmean<<<NBLK, 256, 0, stream>>>(hbuf, gsum);
    final_pred<<<1, 256, 0, stream>>>(gsum, W_pred, b_pred, out);
}